// Round 9
// baseline (384.615 us; speedup 1.0000x reference)
//
#include <hip/hip_runtime.h>
#include <stdint.h>

// LocalAttention: y = LN(x + proj(attn(qkv(x)))). fp32 inputs, fp32 output.
// B=4 L=4096 D=1024 H=16 W=HD=64 -> M=16384 rows.
//
// R16 (on the 345 us R15 composition). Three separable changes:
//  (a) LDS-transposed gemm256 epilogue: after the K-loop the 128 KiB LDS is
//      dead. Dump acc(+bias) to a pad-260 fp32 buffer (<=2-way banks, free),
//      read back row-major: 16 float4 resid loads + 16 vector stores per
//      thread replace 128 scalar stores (+128 scalar resid loads). Global
//      epilogue instructions 256 -> 64, all full sectors.
//  (b) XCD-aligned attn remap: gemm1's XCD swizzle gives XCD x tokens
//      [2048x,2048(x+1)). Bijection x=wid&7; k=wid>>3; b=x>>1; h=k>>5;
//      wi=(x&1)*32+(k&31) puts each attn block on the XCD whose L2/L3
//      holds its window's QKV; proj (same token ownership) reads attn
//      output from the same XCD's L2.
//  (c) merged cast kernel (3 launches -> 1).

typedef __attribute__((ext_vector_type(8))) short short8;
typedef __attribute__((ext_vector_type(4))) float float4v;
typedef unsigned short us;

#define GAS const __attribute__((address_space(1))) void
#define LAS __attribute__((address_space(3))) void

__device__ __forceinline__ float bf2f(us u) {
  return __uint_as_float(((unsigned int)u) << 16);
}
__device__ __forceinline__ us f2bf(float f) {
  unsigned int u = __float_as_uint(f);
  unsigned int r = u + 0x7FFFu + ((u >> 16) & 1u);
  return (us)(r >> 16);
}
__device__ __forceinline__ int4 stage8(const float* p) {
  float4 a = *(const float4*)p;
  float4 b = *(const float4*)(p + 4);
  int4 r;
  us* u = (us*)&r;
  u[0] = f2bf(a.x); u[1] = f2bf(a.y); u[2] = f2bf(a.z); u[3] = f2bf(a.w);
  u[4] = f2bf(b.x); u[5] = f2bf(b.y); u[6] = f2bf(b.z); u[7] = f2bf(b.w);
  return r;
}
__device__ __forceinline__ int4 stage8(const us* p) { return *(const int4*)p; }
__device__ __forceinline__ void stc(us* p, float v) { *p = f2bf(v); }
__device__ __forceinline__ void stc(float* p, float v) { *p = v; }

// ---------------------------------------------------------------------------
// merged fp32 -> bf16 precast for x, Wqkv, Wproj (one launch)
// ---------------------------------------------------------------------------
__global__ __launch_bounds__(256) void cast_all(
    const float* __restrict__ x, const float* __restrict__ wq,
    const float* __restrict__ wp, us* __restrict__ xb, us* __restrict__ wqb,
    us* __restrict__ wpb) {
  const int i = blockIdx.x * 256 + threadIdx.x;
  constexpr int n1 = 16384 * 128;  // x in 8-elem units
  constexpr int n2 = 3072 * 128;
  if (i < n1) {
    *(int4*)(xb + (size_t)i * 8) = stage8(x + (size_t)i * 8);
  } else if (i < n1 + n2) {
    const int j = i - n1;
    *(int4*)(wqb + (size_t)j * 8) = stage8(wq + (size_t)j * 8);
  } else {
    const int j = i - n1 - n2;
    *(int4*)(wpb + (size_t)j * 8) = stage8(wp + (size_t)j * 8);
  }
}

// ---------------------------------------------------------------------------
// 256x256 GEMM, BK=64, 2-barrier K-loop + counted vmcnt prefetch, XCD-chunked
// block remap (R15-proven: 119.7 us QKV, FETCH 94.4 MB, conflicts 0).
// R16: LDS-transposed epilogue (see header).
// ---------------------------------------------------------------------------
template <int N, int K, int EPI, int HM, typename CT>
__global__ __launch_bounds__(512, 1) void gemm256(
    const us* __restrict__ A, const us* __restrict__ Bt,
    const float* __restrict__ bias, const float* __restrict__ resid,
    CT* __restrict__ C) {
  constexpr int NBX = N / 256;
  constexpr int NWG = NBX * 64;  // 16384/256 m-tiles
  __shared__ __align__(16) unsigned char RAW[133120];  // max(128K, 128*260*4)
  us* AsB = (us*)RAW;                  // [2][256*64]
  us* BsB = (us*)(RAW + 65536);        // [2][256*64]
  float* EPIF = (float*)RAW;           // [128][260] epilogue transpose buf
  const int tid = threadIdx.x;
  const int lane = tid & 63;
  const int wave = tid >> 6;   // 0..7
  const int wm = wave >> 2;    // 0..1  (M half)
  const int wn = wave & 3;     // 0..3  (N quarter)
  const int lr = lane & 15, lq = lane >> 4;

  int id = blockIdx.y * NBX + blockIdx.x;
  id = (id & 7) * (NWG / 8) + (id >> 3);  // XCD-contiguous tile ranges
  const int m0 = (id / NBX) * 256;
  const int n0 = (id % NBX) * 256;

  const int trow = tid >> 3;                        // 0..63 (row within 64-row pass)
  const int tcol = (((tid & 7) ^ (trow & 7)) * 8);  // XOR-swizzled src col

  constexpr int NT = K / 64;

  float4v acc[8][4];
#pragma unroll
  for (int i = 0; i < 8; i++)
#pragma unroll
    for (int j = 0; j < 4; j++) acc[i][j] = (float4v)0.0f;

#define STAGE256(buf, t)                                                       \
  do {                                                                         \
    const size_t kof = (size_t)(t) * 64;                                       \
    _Pragma("unroll") for (int q = 0; q < 4; q++) {                            \
      const us* ga = A + (size_t)(m0 + q * 64 + trow) * K + kof + tcol;        \
      __builtin_amdgcn_global_load_lds((GAS*)ga,                               \
          (LAS*)&AsB[(buf)*16384 + (q * 512 + tid) * 8], 16, 0, 0);            \
    }                                                                          \
    _Pragma("unroll") for (int q = 0; q < 4; q++) {                            \
      const us* gb = Bt + (size_t)(n0 + q * 64 + trow) * K + kof + tcol;       \
      __builtin_amdgcn_global_load_lds((GAS*)gb,                               \
          (LAS*)&BsB[(buf)*16384 + (q * 512 + tid) * 8], 16, 0, 0);            \
    }                                                                          \
  } while (0)

  STAGE256(0, 0);  // prologue: tile 0 in flight

  for (int t = 0; t < NT; t++) {
    const int cur = t & 1;
    __builtin_amdgcn_s_barrier();  // B0: tile t-1 reads complete everywhere
    if (t + 1 < NT) {
      STAGE256(cur ^ 1, t + 1);    // overwrite t-1's buffer (safe after B0)
      asm volatile("s_waitcnt vmcnt(8)" ::: "memory");  // tile t landed
    } else {
      asm volatile("s_waitcnt vmcnt(0)" ::: "memory");  // drain last tile
    }
    __builtin_amdgcn_s_barrier();  // B1: tile t visible to all waves

    const us* Ab = AsB + cur * 16384;
    const us* Bb = BsB + cur * 16384;
#pragma unroll
    for (int kk8 = 0; kk8 < 2; kk8++) {
      short8 bf8[4];
#pragma unroll
      for (int nt = 0; nt < 4; nt++) {
        const int row = wn * 64 + nt * 16 + lr;
        bf8[nt] = *(const short8*)&Bb[row * 64 + (((kk8 * 4 + lq) ^ (lr & 7)) * 8)];
      }
#pragma unroll
      for (int mh = 0; mh < 2; mh++) {
        short8 af[4];
#pragma unroll
        for (int mt = 0; mt < 4; mt++) {
          const int row = wm * 128 + mh * 64 + mt * 16 + lr;
          af[mt] = *(const short8*)&Ab[row * 64 + (((kk8 * 4 + lq) ^ (lr & 7)) * 8)];
        }
        __builtin_amdgcn_s_setprio(1);
#pragma unroll
        for (int mt = 0; mt < 4; mt++)
#pragma unroll
          for (int nt = 0; nt < 4; nt++)
            acc[mh * 4 + mt][nt] = __builtin_amdgcn_mfma_f32_16x16x32_bf16(
                af[mt], bf8[nt], acc[mh * 4 + mt][nt], 0, 0, 0);
        __builtin_amdgcn_s_setprio(0);
      }
    }
  }
#undef STAGE256

  float bb[4];
#pragma unroll
  for (int nt = 0; nt < 4; nt++) bb[nt] = bias[n0 + wn * 64 + nt * 16 + lr];

  // ---- LDS-transposed epilogue, two 128-row passes (m-half p) ----
#pragma unroll
  for (int p = 0; p < 2; p++) {
    __builtin_amdgcn_s_barrier();  // staging/prev-pass reads complete
#pragma unroll
    for (int mt = 0; mt < 4; mt++) {
      const int cr = wm * 64 + mt * 16 + lq * 4;  // compact row base
#pragma unroll
      for (int nt = 0; nt < 4; nt++) {
        const int ccol = wn * 64 + nt * 16 + lr;
#pragma unroll
        for (int r = 0; r < 4; r++)
          EPIF[(cr + r) * 260 + ccol] = acc[p * 4 + mt][nt][r] + bb[nt];
      }
    }
    __builtin_amdgcn_s_barrier();  // transpose buffer filled
    const int rr = tid >> 2, cq = tid & 3;
    const int grow = m0 + (rr >> 6) * 128 + p * 64 + (rr & 63);
#pragma unroll
    for (int i = 0; i < 16; i++) {
      const int ii = (i + cq * 4) & 15;  // bank-rotation: 2-way max
      float4 v = *(const float4*)&EPIF[rr * 260 + cq * 64 + ii * 4];
      const int gcol = n0 + cq * 64 + ii * 4;
      size_t idx;
      if (HM) {
        // head-major: [mat][b*16+h][tok][d]; 4 cols contiguous within head
        const int mat = gcol >> 10, hh = (gcol >> 6) & 15, d = gcol & 63;
        idx = (size_t)mat * (16384u * 1024u) +
              (size_t)((grow >> 12) * 16 + hh) * (4096u * 64u) +
              (size_t)(grow & 4095) * 64 + d;
      } else {
        idx = (size_t)grow * N + gcol;
      }
      if (EPI) {
        const float4 rv = *(const float4*)&resid[idx];
        v.x += rv.x; v.y += rv.y; v.z += rv.z; v.w += rv.w;
      }
      if constexpr (sizeof(CT) == 2) {
        us pk[4] = {f2bf(v.x), f2bf(v.y), f2bf(v.z), f2bf(v.w)};
        *(int2*)&C[idx] = *(int2*)pk;
      } else {
        *(float4*)&C[idx] = *(float4*)&v;
      }
    }
  }
}

// ---------------------------------------------------------------------------
// MFMA windowed attention, head-major input, 1 window per block, coalesced
// O store (R15). R16: XCD-aligned blockIdx decode -- block j runs on XCD
// j%8, which owns tokens [2048*(j%8), ...) from gemm1's swizzle.
// ---------------------------------------------------------------------------
__global__ __launch_bounds__(256) void attn_mfma(
    const us* __restrict__ qkv, us* __restrict__ attn) {
  __shared__ __align__(16) us Vt[64 * 64];       // elem(d,j) at d*64+((j>>3)^(d&7))*8+(j&7)
  __shared__ __align__(16) us Pl[4 * 16 * 64];   // per-wave 16x64, swizzled
  const int wid = blockIdx.x;
  const int x = wid & 7;          // target XCD = token owner
  const int k = wid >> 3;
  const int b = x >> 1;
  const int h = k >> 5;
  const int wi = ((x & 1) << 5) | (k & 31);
  const int tid = threadIdx.x;
  const int lane = tid & 63;
  const int w = tid >> 6;
  const int lr = lane & 15, lq = lane >> 4;
  const int rowbase = b * 4096 + wi * 64;

  // head-major window bases: contiguous 64x64 bf16 tiles
  const us* Qb = qkv + (size_t)(b * 16 + h) * (4096u * 64u) + (size_t)wi * 4096;
  const us* Kb = Qb + (size_t)16384 * 1024;
  const us* Vb = Kb + (size_t)16384 * 1024;

  // ---- stage V^T (swizzled): wave w covers d in [16w,16w+16) for all tokens
  {
    const int r = lane;  // token in window
    const int cs = w * 16;
    const us* vsrc = Vb + (size_t)r * 64 + cs;
    int4 v0 = *(const int4*)vsrc;
    int4 v1 = *(const int4*)(vsrc + 8);
    const us* vv0 = (const us*)&v0;
    const us* vv1 = (const us*)&v1;
#pragma unroll
    for (int i = 0; i < 8; i++) {
      const int d = cs + i;
      Vt[d * 64 + (((r >> 3) ^ (d & 7)) * 8) + (r & 7)] = vv0[i];
    }
#pragma unroll
    for (int i = 0; i < 8; i++) {
      const int d = cs + 8 + i;
      Vt[d * 64 + (((r >> 3) ^ (d & 7)) * 8) + (r & 7)] = vv1[i];
    }
  }

  // ---- S = Q K^T (rows 16w..16w+15), frags from global (L1-local)
  short8 aq[2];
  {
    const us* qrow = Qb + (size_t)(w * 16 + lr) * 64 + lq * 8;
    aq[0] = *(const short8*)qrow;
    aq[1] = *(const short8*)(qrow + 32);
  }
  float4v s[4];
#pragma unroll
  for (int nt = 0; nt < 4; nt++) s[nt] = (float4v)0.0f;
#pragma unroll
  for (int kk8 = 0; kk8 < 2; kk8++) {
#pragma unroll
    for (int nt = 0; nt < 4; nt++) {
      const us* krow = Kb + (size_t)(nt * 16 + lr) * 64 + kk8 * 32 + lq * 8;
      short8 bk = *(const short8*)krow;
      s[nt] = __builtin_amdgcn_mfma_f32_16x16x32_bf16(aq[kk8], bk, s[nt], 0, 0, 0);
    }
  }

  // ---- softmax per row
  float p[4][4];  // [nt][r]
#pragma unroll
  for (int r = 0; r < 4; r++) {
    float mx = -1e30f;
#pragma unroll
    for (int nt = 0; nt < 4; nt++) {
      s[nt][r] *= 0.125f;
      mx = fmaxf(mx, s[nt][r]);
    }
    mx = fmaxf(mx, __shfl_xor(mx, 1));
    mx = fmaxf(mx, __shfl_xor(mx, 2));
    mx = fmaxf(mx, __shfl_xor(mx, 4));
    mx = fmaxf(mx, __shfl_xor(mx, 8));
    float sum = 0.f;
#pragma unroll
    for (int nt = 0; nt < 4; nt++) {
      p[nt][r] = __expf(s[nt][r] - mx);
      sum += p[nt][r];
    }
    sum += __shfl_xor(sum, 1);
    sum += __shfl_xor(sum, 2);
    sum += __shfl_xor(sum, 4);
    sum += __shfl_xor(sum, 8);
    const float inv = 1.0f / sum;
#pragma unroll
    for (int nt = 0; nt < 4; nt++) p[nt][r] *= inv;
  }

  // ---- P -> LDS (per-wave region, swizzled), C-layout source
  us* pw = Pl + w * 1024;
#pragma unroll
  for (int nt = 0; nt < 4; nt++) {
    const int c = nt * 16 + lr;
#pragma unroll
    for (int r = 0; r < 4; r++) {
      const int row = lq * 4 + r;
      pw[row * 64 + (((c >> 3) ^ (row & 7)) * 8) + (c & 7)] = f2bf(p[nt][r]);
    }
  }
  __syncthreads();  // Vt (cross-wave) + P visible

  // ---- O = P V  (A-frag from Pl, B-frag from Vt)
  float4v o[4];
#pragma unroll
  for (int nt = 0; nt < 4; nt++) o[nt] = (float4v)0.0f;
#pragma unroll
  for (int kk8 = 0; kk8 < 2; kk8++) {
    short8 pa = *(const short8*)&pw[lr * 64 + (((lq + kk8 * 4) ^ (lr & 7)) * 8)];
#pragma unroll
    for (int nt = 0; nt < 4; nt++) {
      const int d = nt * 16 + lr;
      short8 vb = *(const short8*)&Vt[d * 64 + (((lq + kk8 * 4) ^ (d & 7)) * 8)];
      o[nt] = __builtin_amdgcn_mfma_f32_16x16x32_bf16(pa, vb, o[nt], 0, 0, 0);
    }
  }

  // ---- O -> per-wave LDS (wave-private; same-wave lgkm ordering), then
  // coalesced 2x16B stores per lane (full 128B row segments).
#pragma unroll
  for (int nt = 0; nt < 4; nt++) {
    const int c = nt * 16 + lr;
#pragma unroll
    for (int r = 0; r < 4; r++) {
      const int row = lq * 4 + r;
      pw[row * 64 + (((c >> 3) ^ (row & 7)) * 8) + (c & 7)] = f2bf(o[nt][r]);
    }
  }
  {
    const int row = lr;
    const int g0 = ((lq * 2) ^ (row & 7)) * 8;
    const int g1 = ((lq * 2 + 1) ^ (row & 7)) * 8;
    int4 v0 = *(const int4*)&pw[row * 64 + g0];
    int4 v1 = *(const int4*)&pw[row * 64 + g1];
    us* dst = attn + (size_t)(rowbase + w * 16 + row) * 1024 + h * 64 + lq * 16;
    *(int4*)dst = v0;
    *(int4*)(dst + 8) = v1;
  }
}

// ---------------------------------------------------------------------------
// FALLBACK GEMM (R5-proven, VGPR staging + convert, unswizzled)
// ---------------------------------------------------------------------------
template <int N, int K, int EPI, typename AT, typename CT>
__global__ __launch_bounds__(256) void gemm_bt(
    const AT* __restrict__ A, const float* __restrict__ Bt,
    const float* __restrict__ bias, const float* __restrict__ resid,
    CT* __restrict__ C) {
  __shared__ __align__(16) us As[128 * 64];
  __shared__ __align__(16) us Bs[128 * 64];
  const int tid = threadIdx.x;
  const int lane = tid & 63;
  const int wave = tid >> 6;
  const int wm = wave >> 1, wn = wave & 1;
  const int lr = lane & 15, lq = lane >> 4;
  const int m0 = blockIdx.y * 128;
  const int n0 = blockIdx.x * 128;
  const int trow = tid >> 3;
  const int tcol = (tid & 7) * 8;

  float4v acc[4][4];
#pragma unroll
  for (int i = 0; i < 4; i++)
#pragma unroll
    for (int j = 0; j < 4; j++) acc[i][j] = (float4v)0.0f;

  for (int k0 = 0; k0 < K; k0 += 64) {
    int4 av[4], bv[4];
#pragma unroll
    for (int p = 0; p < 4; p++) {
      av[p] = stage8(A + (size_t)(m0 + p * 32 + trow) * K + k0 + tcol);
      bv[p] = stage8(Bt + (size_t)(n0 + p * 32 + trow) * K + k0 + tcol);
    }
#pragma unroll
    for (int p = 0; p < 4; p++) {
      *(int4*)&As[(p * 256 + tid) * 8] = av[p];
      *(int4*)&Bs[(p * 256 + tid) * 8] = bv[p];
    }
    __syncthreads();
#pragma unroll
    for (int kk = 0; kk < 64; kk += 32) {
      short8 af[4], bfv[4];
#pragma unroll
      for (int mt = 0; mt < 4; mt++)
        af[mt] = *(const short8*)&As[(wm * 64 + mt * 16 + lr) * 64 + kk + lq * 8];
#pragma unroll
      for (int nt = 0; nt < 4; nt++)
        bfv[nt] = *(const short8*)&Bs[(wn * 64 + nt * 16 + lr) * 64 + kk + lq * 8];
#pragma unroll
      for (int mt = 0; mt < 4; mt++)
#pragma unroll
        for (int nt = 0; nt < 4; nt++)
          acc[mt][nt] = __builtin_amdgcn_mfma_f32_16x16x32_bf16(
              af[mt], bfv[nt], acc[mt][nt], 0, 0, 0);
    }
    __syncthreads();
  }

  float bb[4];
#pragma unroll
  for (int nt = 0; nt < 4; nt++) bb[nt] = bias[n0 + wn * 64 + nt * 16 + lr];
#pragma unroll
  for (int mt = 0; mt < 4; mt++) {
    const int rbase = m0 + wm * 64 + mt * 16 + lq * 4;
#pragma unroll
    for (int nt = 0; nt < 4; nt++) {
      const int col = n0 + wn * 64 + nt * 16 + lr;
#pragma unroll
      for (int r = 0; r < 4; r++) {
        float v = acc[mt][nt][r] + bb[nt];
        size_t idx = (size_t)(rbase + r) * N + col;
        if (EPI) v += resid[idx];
        stc(&C[idx], v);
      }
    }
  }
}

// ---------------------------------------------------------------------------
// Fallback VALU attention (R5-proven, row-major qkv)
// ---------------------------------------------------------------------------
__global__ __launch_bounds__(256) void attn_win(
    const us* __restrict__ qkv, us* __restrict__ attn) {
  __shared__ float qs[64][65];
  __shared__ float ks[64][65];
  __shared__ float vs[64][65];
  const int wid = blockIdx.x;
  const int wi = wid & 63;
  const int h = (wid >> 6) & 15;
  const int b = wid >> 10;
  const int t = threadIdx.x;
  const int rowbase = b * 4096 + wi * 64;
  {
    const int r = t >> 2;
    const int cs = (t & 3) * 16;
    const us* base = qkv + (size_t)(rowbase + r) * 3072 + h * 64 + cs;
#pragma unroll
    for (int s = 0; s < 3; s++) {
      float* dst = (s == 0) ? &qs[r][cs] : (s == 1) ? &ks[r][cs] : &vs[r][cs];
      const us* src = base + s * 1024;
#pragma unroll
      for (int half = 0; half < 2; half++) {
        int4 dv = *(const int4*)(src + half * 8);
        const us* tp = (const us*)&dv;
#pragma unroll
        for (int i = 0; i < 8; i++) dst[half * 8 + i] = bf2f(tp[i]);
      }
    }
  }
  __syncthreads();
  const int r0 = (t >> 4) * 4;
  const int c0 = (t & 15) * 4;
  float acc[4][4] = {};
#pragma unroll 8
  for (int k = 0; k < 64; k++) {
    float qv[4], kv[4];
#pragma unroll
    for (int i = 0; i < 4; i++) qv[i] = qs[r0 + i][k];
#pragma unroll
    for (int j = 0; j < 4; j++) kv[j] = ks[c0 + j][k];
#pragma unroll
    for (int i = 0; i < 4; i++)
#pragma unroll
      for (int j = 0; j < 4; j++) acc[i][j] += qv[i] * kv[j];
  }
  __syncthreads();
#pragma unroll
  for (int i = 0; i < 4; i++)
#pragma unroll
    for (int j = 0; j < 4; j++) qs[r0 + i][c0 + j] = acc[i][j] * 0.125f;
  __syncthreads();
  {
    const int rr = t >> 2;
    const int cs = (t & 3) * 16;
    float pv[16];
    float m = -1e30f;
#pragma unroll
    for (int i = 0; i < 16; i++) {
      pv[i] = qs[rr][cs + i];
      m = fmaxf(m, pv[i]);
    }
    m = fmaxf(m, __shfl_xor(m, 1));
    m = fmaxf(m, __shfl_xor(m, 2));
    float ssum = 0.f;
#pragma unroll
    for (int i = 0; i < 16; i++) {
      pv[i] = __expf(pv[i] - m);
      ssum += pv[i];
    }
    ssum += __shfl_xor(ssum, 1);
    ssum += __shfl_xor(ssum, 2);
    const float inv = 1.0f / ssum;
#pragma unroll
    for (int i = 0; i < 16; i++) qs[rr][cs + i] = pv[i] * inv;
  }
  __syncthreads();
  float o[4][4] = {};
#pragma unroll 8
  for (int k = 0; k < 64; k++) {
    float pr[4], vv[4];
#pragma unroll
    for (int i = 0; i < 4; i++) pr[i] = qs[r0 + i][k];
#pragma unroll
    for (int j = 0; j < 4; j++) vv[j] = vs[k][c0 + j];
#pragma unroll
    for (int i = 0; i < 4; i++)
#pragma unroll
      for (int j = 0; j < 4; j++) o[i][j] += pr[i] * vv[j];
  }
#pragma unroll
  for (int i = 0; i < 4; i++)
#pragma unroll
    for (int j = 0; j < 4; j++)
      attn[(size_t)(rowbase + r0 + i) * 1024 + h * 64 + c0 + j] = f2bf(o[i][j]);
}

// ---------------------------------------------------------------------------
// In-place fp32 LayerNorm, one WAVE per row: no LDS, no barriers.
// ---------------------------------------------------------------------------
__global__ __launch_bounds__(256) void ln_wave(
    float* __restrict__ y, const float* __restrict__ gamma,
    const float* __restrict__ beta) {
  const int row = blockIdx.x * 4 + (threadIdx.x >> 6);
  const int lane = threadIdx.x & 63;
  float* yr = y + (size_t)row * 1024;
  float4 v[4];
  float s1 = 0.f, s2 = 0.f;
#pragma unroll
  for (int i = 0; i < 4; i++) {
    v[i] = *(const float4*)(yr + (i * 64 + lane) * 4);
    s1 += v[i].x + v[i].y + v[i].z + v[i].w;
    s2 += v[i].x * v[i].x + v[i].y * v[i].y + v[i].z * v[i].z + v[i].w * v[i].w;
  }
#pragma unroll
  for (int off = 32; off > 0; off >>= 1) {
    s1 += __shfl_xor(s1, off);
    s2 += __shfl_xor(s2, off);
  }
  const float mean = s1 * (1.0f / 1024.0f);
  const float var = s2 * (1.0f / 1024.0f) - mean * mean;
  const float rstd = rsqrtf(var + 1e-5f);
#pragma unroll
  for (int i = 0; i < 4; i++) {
    float4 g = *(const float4*)(gamma + (i * 64 + lane) * 4);
    float4 bt = *(const float4*)(beta + (i * 64 + lane) * 4);
    float4 o;
    o.x = (v[i].x - mean) * rstd * g.x + bt.x;
    o.y = (v[i].y - mean) * rstd * g.y + bt.y;
    o.z = (v[i].z - mean) * rstd * g.z + bt.z;
    o.w = (v[i].w - mean) * rstd * g.w + bt.w;
    *(float4*)(yr + (i * 64 + lane) * 4) = o;
  }
}

// ---------------------------------------------------------------------------
extern "C" void kernel_launch(void* const* d_in, const int* in_sizes, int n_in,
                              void* d_out, int out_size, void* d_ws,
                              size_t ws_size, hipStream_t stream) {
  const float* x = (const float*)d_in[0];
  const float* Wqkv = (const float*)d_in[1];
  const float* bqkv = (const float*)d_in[2];
  const float* Wproj = (const float*)d_in[3];
  const float* bproj = (const float*)d_in[4];
  const float* gamma = (const float*)d_in[5];
  const float* beta = (const float*)d_in[6];
  float* out = (float*)d_out;

  us* qkv = (us*)d_ws;                        // 16384*3072 (100.7 MB)
  us* attn = qkv + (size_t)16384 * 3072;      // 16384*1024 (33.6 MB)
  us* xb = attn + (size_t)16384 * 1024;       // 16384*1024 (33.6 MB)
  us* Wqkvb = xb + (size_t)16384 * 1024;      // 3072*1024  (6.3 MB)
  us* Wprojb = Wqkvb + (size_t)3072 * 1024;   // 1024*1024  (2.1 MB)
  const size_t need =
      ((size_t)16384 * 3072 + 3 * (size_t)16384 * 1024 + (size_t)3072 * 1024 +
       (size_t)1024 * 1024) * sizeof(us);

  if (ws_size >= need) {
    constexpr int ncast = 16384 * 128 + 3072 * 128 + 1024 * 128;  // 8-elem units
    cast_all<<<ncast / 256, 256, 0, stream>>>(x, Wqkv, Wproj, xb, Wqkvb,
                                              Wprojb);
    gemm256<3072, 1024, 0, 1, us><<<dim3(12, 64), 512, 0, stream>>>(
        xb, Wqkvb, bqkv, nullptr, qkv);
    attn_mfma<<<4096, 256, 0, stream>>>(qkv, attn);
    gemm256<1024, 1024, 1, 0, float><<<dim3(4, 64), 512, 0, stream>>>(
        attn, Wprojb, bproj, x, out);
  } else {
    gemm_bt<3072, 1024, 0, float, us><<<dim3(24, 128), 256, 0, stream>>>(
        x, Wqkv, bqkv, nullptr, qkv);
    attn_win<<<4096, 256, 0, stream>>>(qkv, attn);
    gemm_bt<1024, 1024, 1, us, float><<<dim3(8, 128), 256, 0, stream>>>(
        attn, Wproj, bproj, x, out);
  }
  ln_wave<<<4096, 256, 0, stream>>>(out, gamma, beta);
}

// Round 10
// 346.469 us; speedup vs baseline: 1.1101x; 1.1101x over previous
//
#include <hip/hip_runtime.h>
#include <stdint.h>

// LocalAttention: y = LN(x + proj(attn(qkv(x)))). fp32 inputs, fp32 output.
// B=4 L=4096 D=1024 H=16 W=HD=64 -> M=16384 rows.
//
// R17: surgical revert of R16(a). R16's LDS-transposed epilogue inflated
// WRITE_SIZE 98.3->121.4 MB (adjacent lanes wrote different heads/rotated
// 8B fragments -> partial sectors) and cost gemm1 +31 us. The old scalar
// epilogue was already full-sector (R15 WRITE exactly 98304 KB): HW write
// combining handles the 16-lane 32B runs. gemm256 restored to the R15
// version verbatim (119.7 us QKV, FETCH 94.4 MB, conflicts 0, XCD remap).
// Kept from R16 (exonerated by the WRITE-counter attribution):
//  - cast_all merged precast (3 launches -> 1)
//  - XCD-aligned attn blockIdx decode (attn block on the XCD owning its
//    tokens under gemm1's swizzle; proj reads from same-XCD L2)
// Plus R15's coalesced attn O-store and ln_wave.

typedef __attribute__((ext_vector_type(8))) short short8;
typedef __attribute__((ext_vector_type(4))) float float4v;
typedef unsigned short us;

#define GAS const __attribute__((address_space(1))) void
#define LAS __attribute__((address_space(3))) void

__device__ __forceinline__ float bf2f(us u) {
  return __uint_as_float(((unsigned int)u) << 16);
}
__device__ __forceinline__ us f2bf(float f) {
  unsigned int u = __float_as_uint(f);
  unsigned int r = u + 0x7FFFu + ((u >> 16) & 1u);
  return (us)(r >> 16);
}
__device__ __forceinline__ int4 stage8(const float* p) {
  float4 a = *(const float4*)p;
  float4 b = *(const float4*)(p + 4);
  int4 r;
  us* u = (us*)&r;
  u[0] = f2bf(a.x); u[1] = f2bf(a.y); u[2] = f2bf(a.z); u[3] = f2bf(a.w);
  u[4] = f2bf(b.x); u[5] = f2bf(b.y); u[6] = f2bf(b.z); u[7] = f2bf(b.w);
  return r;
}
__device__ __forceinline__ int4 stage8(const us* p) { return *(const int4*)p; }
__device__ __forceinline__ void stc(us* p, float v) { *p = f2bf(v); }
__device__ __forceinline__ void stc(float* p, float v) { *p = v; }

// ---------------------------------------------------------------------------
// merged fp32 -> bf16 precast for x, Wqkv, Wproj (one launch)
// ---------------------------------------------------------------------------
__global__ __launch_bounds__(256) void cast_all(
    const float* __restrict__ x, const float* __restrict__ wq,
    const float* __restrict__ wp, us* __restrict__ xb, us* __restrict__ wqb,
    us* __restrict__ wpb) {
  const int i = blockIdx.x * 256 + threadIdx.x;
  constexpr int n1 = 16384 * 128;  // x in 8-elem units
  constexpr int n2 = 3072 * 128;
  if (i < n1) {
    *(int4*)(xb + (size_t)i * 8) = stage8(x + (size_t)i * 8);
  } else if (i < n1 + n2) {
    const int j = i - n1;
    *(int4*)(wqb + (size_t)j * 8) = stage8(wq + (size_t)j * 8);
  } else {
    const int j = i - n1 - n2;
    *(int4*)(wpb + (size_t)j * 8) = stage8(wp + (size_t)j * 8);
  }
}

// ---------------------------------------------------------------------------
// 256x256 GEMM, BK=64, 2-barrier K-loop + counted vmcnt prefetch, XCD-chunked
// block remap, scalar epilogue (R15-proven: 119.7 us QKV, WRITE full-sector,
// FETCH 94.4 MB, conflicts 0). 512 threads = 8 waves (2M x 4N), per-wave
// 128x64 output. LDS: 2-deep double buffer, 128 KiB (1 block/CU).
// ---------------------------------------------------------------------------
template <int N, int K, int EPI, int HM, typename CT>
__global__ __launch_bounds__(512, 1) void gemm256(
    const us* __restrict__ A, const us* __restrict__ Bt,
    const float* __restrict__ bias, const float* __restrict__ resid,
    CT* __restrict__ C) {
  constexpr int NBX = N / 256;
  constexpr int NWG = NBX * 64;  // 16384/256 m-tiles
  __shared__ __align__(16) us As[2][256 * 64];
  __shared__ __align__(16) us Bs[2][256 * 64];
  const int tid = threadIdx.x;
  const int lane = tid & 63;
  const int wave = tid >> 6;   // 0..7
  const int wm = wave >> 2;    // 0..1  (M half)
  const int wn = wave & 3;     // 0..3  (N quarter)
  const int lr = lane & 15, lq = lane >> 4;

  int id = blockIdx.y * NBX + blockIdx.x;
  id = (id & 7) * (NWG / 8) + (id >> 3);  // XCD-contiguous tile ranges
  const int m0 = (id / NBX) * 256;
  const int n0 = (id % NBX) * 256;

  const int trow = tid >> 3;                        // 0..63 (row within 64-row pass)
  const int tcol = (((tid & 7) ^ (trow & 7)) * 8);  // XOR-swizzled src col

  constexpr int NT = K / 64;

  float4v acc[8][4];
#pragma unroll
  for (int i = 0; i < 8; i++)
#pragma unroll
    for (int j = 0; j < 4; j++) acc[i][j] = (float4v)0.0f;

#define STAGE256(buf, t)                                                       \
  do {                                                                         \
    const size_t kof = (size_t)(t) * 64;                                       \
    _Pragma("unroll") for (int q = 0; q < 4; q++) {                            \
      const us* ga = A + (size_t)(m0 + q * 64 + trow) * K + kof + tcol;        \
      __builtin_amdgcn_global_load_lds((GAS*)ga,                               \
          (LAS*)&As[buf][(q * 512 + tid) * 8], 16, 0, 0);                      \
    }                                                                          \
    _Pragma("unroll") for (int q = 0; q < 4; q++) {                            \
      const us* gb = Bt + (size_t)(n0 + q * 64 + trow) * K + kof + tcol;       \
      __builtin_amdgcn_global_load_lds((GAS*)gb,                               \
          (LAS*)&Bs[buf][(q * 512 + tid) * 8], 16, 0, 0);                      \
    }                                                                          \
  } while (0)

  STAGE256(0, 0);  // prologue: tile 0 in flight

  for (int t = 0; t < NT; t++) {
    const int cur = t & 1;
    __builtin_amdgcn_s_barrier();  // B0: tile t-1 reads complete everywhere
    if (t + 1 < NT) {
      STAGE256(cur ^ 1, t + 1);    // overwrite t-1's buffer (safe after B0)
      asm volatile("s_waitcnt vmcnt(8)" ::: "memory");  // tile t landed
    } else {
      asm volatile("s_waitcnt vmcnt(0)" ::: "memory");  // drain last tile
    }
    __builtin_amdgcn_s_barrier();  // B1: tile t visible to all waves

    const us* Ab = As[cur];
    const us* Bb = Bs[cur];
#pragma unroll
    for (int kk8 = 0; kk8 < 2; kk8++) {
      short8 bf8[4];
#pragma unroll
      for (int nt = 0; nt < 4; nt++) {
        const int row = wn * 64 + nt * 16 + lr;
        bf8[nt] = *(const short8*)&Bb[row * 64 + (((kk8 * 4 + lq) ^ (lr & 7)) * 8)];
      }
#pragma unroll
      for (int mh = 0; mh < 2; mh++) {
        short8 af[4];
#pragma unroll
        for (int mt = 0; mt < 4; mt++) {
          const int row = wm * 128 + mh * 64 + mt * 16 + lr;
          af[mt] = *(const short8*)&Ab[row * 64 + (((kk8 * 4 + lq) ^ (lr & 7)) * 8)];
        }
        __builtin_amdgcn_s_setprio(1);
#pragma unroll
        for (int mt = 0; mt < 4; mt++)
#pragma unroll
          for (int nt = 0; nt < 4; nt++)
            acc[mh * 4 + mt][nt] = __builtin_amdgcn_mfma_f32_16x16x32_bf16(
                af[mt], bf8[nt], acc[mh * 4 + mt][nt], 0, 0, 0);
        __builtin_amdgcn_s_setprio(0);
      }
    }
  }
#undef STAGE256

  float bb[4];
#pragma unroll
  for (int nt = 0; nt < 4; nt++) bb[nt] = bias[n0 + wn * 64 + nt * 16 + lr];
#pragma unroll
  for (int mh = 0; mh < 2; mh++)
#pragma unroll
    for (int mt = 0; mt < 4; mt++) {
      const int rbase = m0 + wm * 128 + mh * 64 + mt * 16 + lq * 4;
#pragma unroll
      for (int nt = 0; nt < 4; nt++) {
        const int col = n0 + wn * 64 + nt * 16 + lr;
#pragma unroll
        for (int r = 0; r < 4; r++) {
          float v = acc[mh * 4 + mt][nt][r] + bb[nt];
          const int row = rbase + r;
          size_t idx;
          if (HM) {
            // head-major: [mat][b*16+h][tok][d]
            const int mat = col >> 10, hh = (col >> 6) & 15, d = col & 63;
            idx = (size_t)mat * (16384u * 1024u) +
                  (size_t)((row >> 12) * 16 + hh) * (4096u * 64u) +
                  (size_t)(row & 4095) * 64 + d;
          } else {
            idx = (size_t)row * N + col;
          }
          if (EPI) v += resid[idx];
          stc(&C[idx], v);
        }
      }
    }
}

// ---------------------------------------------------------------------------
// MFMA windowed attention, head-major input, 1 window per block, coalesced
// O store (R15), XCD-aligned blockIdx decode (R16b: block j runs on XCD
// j%8, which owns tokens [2048*(j%8), ...) from gemm1's swizzle).
// ---------------------------------------------------------------------------
__global__ __launch_bounds__(256) void attn_mfma(
    const us* __restrict__ qkv, us* __restrict__ attn) {
  __shared__ __align__(16) us Vt[64 * 64];       // elem(d,j) at d*64+((j>>3)^(d&7))*8+(j&7)
  __shared__ __align__(16) us Pl[4 * 16 * 64];   // per-wave 16x64, swizzled
  const int wid = blockIdx.x;
  const int x = wid & 7;          // target XCD = token owner
  const int k = wid >> 3;
  const int b = x >> 1;
  const int h = k >> 5;
  const int wi = ((x & 1) << 5) | (k & 31);
  const int tid = threadIdx.x;
  const int lane = tid & 63;
  const int w = tid >> 6;
  const int lr = lane & 15, lq = lane >> 4;
  const int rowbase = b * 4096 + wi * 64;

  // head-major window bases: contiguous 64x64 bf16 tiles
  const us* Qb = qkv + (size_t)(b * 16 + h) * (4096u * 64u) + (size_t)wi * 4096;
  const us* Kb = Qb + (size_t)16384 * 1024;
  const us* Vb = Kb + (size_t)16384 * 1024;

  // ---- stage V^T (swizzled): wave w covers d in [16w,16w+16) for all tokens
  {
    const int r = lane;  // token in window
    const int cs = w * 16;
    const us* vsrc = Vb + (size_t)r * 64 + cs;
    int4 v0 = *(const int4*)vsrc;
    int4 v1 = *(const int4*)(vsrc + 8);
    const us* vv0 = (const us*)&v0;
    const us* vv1 = (const us*)&v1;
#pragma unroll
    for (int i = 0; i < 8; i++) {
      const int d = cs + i;
      Vt[d * 64 + (((r >> 3) ^ (d & 7)) * 8) + (r & 7)] = vv0[i];
    }
#pragma unroll
    for (int i = 0; i < 8; i++) {
      const int d = cs + 8 + i;
      Vt[d * 64 + (((r >> 3) ^ (d & 7)) * 8) + (r & 7)] = vv1[i];
    }
  }

  // ---- S = Q K^T (rows 16w..16w+15), frags from global (L1-local)
  short8 aq[2];
  {
    const us* qrow = Qb + (size_t)(w * 16 + lr) * 64 + lq * 8;
    aq[0] = *(const short8*)qrow;
    aq[1] = *(const short8*)(qrow + 32);
  }
  float4v s[4];
#pragma unroll
  for (int nt = 0; nt < 4; nt++) s[nt] = (float4v)0.0f;
#pragma unroll
  for (int kk8 = 0; kk8 < 2; kk8++) {
#pragma unroll
    for (int nt = 0; nt < 4; nt++) {
      const us* krow = Kb + (size_t)(nt * 16 + lr) * 64 + kk8 * 32 + lq * 8;
      short8 bk = *(const short8*)krow;
      s[nt] = __builtin_amdgcn_mfma_f32_16x16x32_bf16(aq[kk8], bk, s[nt], 0, 0, 0);
    }
  }

  // ---- softmax per row
  float p[4][4];  // [nt][r]
#pragma unroll
  for (int r = 0; r < 4; r++) {
    float mx = -1e30f;
#pragma unroll
    for (int nt = 0; nt < 4; nt++) {
      s[nt][r] *= 0.125f;
      mx = fmaxf(mx, s[nt][r]);
    }
    mx = fmaxf(mx, __shfl_xor(mx, 1));
    mx = fmaxf(mx, __shfl_xor(mx, 2));
    mx = fmaxf(mx, __shfl_xor(mx, 4));
    mx = fmaxf(mx, __shfl_xor(mx, 8));
    float sum = 0.f;
#pragma unroll
    for (int nt = 0; nt < 4; nt++) {
      p[nt][r] = __expf(s[nt][r] - mx);
      sum += p[nt][r];
    }
    sum += __shfl_xor(sum, 1);
    sum += __shfl_xor(sum, 2);
    sum += __shfl_xor(sum, 4);
    sum += __shfl_xor(sum, 8);
    const float inv = 1.0f / sum;
#pragma unroll
    for (int nt = 0; nt < 4; nt++) p[nt][r] *= inv;
  }

  // ---- P -> LDS (per-wave region, swizzled), C-layout source
  us* pw = Pl + w * 1024;
#pragma unroll
  for (int nt = 0; nt < 4; nt++) {
    const int c = nt * 16 + lr;
#pragma unroll
    for (int r = 0; r < 4; r++) {
      const int row = lq * 4 + r;
      pw[row * 64 + (((c >> 3) ^ (row & 7)) * 8) + (c & 7)] = f2bf(p[nt][r]);
    }
  }
  __syncthreads();  // Vt (cross-wave) + P visible

  // ---- O = P V  (A-frag from Pl, B-frag from Vt)
  float4v o[4];
#pragma unroll
  for (int nt = 0; nt < 4; nt++) o[nt] = (float4v)0.0f;
#pragma unroll
  for (int kk8 = 0; kk8 < 2; kk8++) {
    short8 pa = *(const short8*)&pw[lr * 64 + (((lq + kk8 * 4) ^ (lr & 7)) * 8)];
#pragma unroll
    for (int nt = 0; nt < 4; nt++) {
      const int d = nt * 16 + lr;
      short8 vb = *(const short8*)&Vt[d * 64 + (((lq + kk8 * 4) ^ (d & 7)) * 8)];
      o[nt] = __builtin_amdgcn_mfma_f32_16x16x32_bf16(pa, vb, o[nt], 0, 0, 0);
    }
  }

  // ---- O -> per-wave LDS (wave-private; same-wave lgkm ordering), then
  // coalesced 2x16B stores per lane (full 128B row segments).
#pragma unroll
  for (int nt = 0; nt < 4; nt++) {
    const int c = nt * 16 + lr;
#pragma unroll
    for (int r = 0; r < 4; r++) {
      const int row = lq * 4 + r;
      pw[row * 64 + (((c >> 3) ^ (row & 7)) * 8) + (c & 7)] = f2bf(o[nt][r]);
    }
  }
  {
    const int row = lr;
    const int g0 = ((lq * 2) ^ (row & 7)) * 8;
    const int g1 = ((lq * 2 + 1) ^ (row & 7)) * 8;
    int4 v0 = *(const int4*)&pw[row * 64 + g0];
    int4 v1 = *(const int4*)&pw[row * 64 + g1];
    us* dst = attn + (size_t)(rowbase + w * 16 + row) * 1024 + h * 64 + lq * 16;
    *(int4*)dst = v0;
    *(int4*)(dst + 8) = v1;
  }
}

// ---------------------------------------------------------------------------
// FALLBACK GEMM (R5-proven, VGPR staging + convert, unswizzled)
// ---------------------------------------------------------------------------
template <int N, int K, int EPI, typename AT, typename CT>
__global__ __launch_bounds__(256) void gemm_bt(
    const AT* __restrict__ A, const float* __restrict__ Bt,
    const float* __restrict__ bias, const float* __restrict__ resid,
    CT* __restrict__ C) {
  __shared__ __align__(16) us As[128 * 64];
  __shared__ __align__(16) us Bs[128 * 64];
  const int tid = threadIdx.x;
  const int lane = tid & 63;
  const int wave = tid >> 6;
  const int wm = wave >> 1, wn = wave & 1;
  const int lr = lane & 15, lq = lane >> 4;
  const int m0 = blockIdx.y * 128;
  const int n0 = blockIdx.x * 128;
  const int trow = tid >> 3;
  const int tcol = (tid & 7) * 8;

  float4v acc[4][4];
#pragma unroll
  for (int i = 0; i < 4; i++)
#pragma unroll
    for (int j = 0; j < 4; j++) acc[i][j] = (float4v)0.0f;

  for (int k0 = 0; k0 < K; k0 += 64) {
    int4 av[4], bv[4];
#pragma unroll
    for (int p = 0; p < 4; p++) {
      av[p] = stage8(A + (size_t)(m0 + p * 32 + trow) * K + k0 + tcol);
      bv[p] = stage8(Bt + (size_t)(n0 + p * 32 + trow) * K + k0 + tcol);
    }
#pragma unroll
    for (int p = 0; p < 4; p++) {
      *(int4*)&As[(p * 256 + tid) * 8] = av[p];
      *(int4*)&Bs[(p * 256 + tid) * 8] = bv[p];
    }
    __syncthreads();
#pragma unroll
    for (int kk = 0; kk < 64; kk += 32) {
      short8 af[4], bfv[4];
#pragma unroll
      for (int mt = 0; mt < 4; mt++)
        af[mt] = *(const short8*)&As[(wm * 64 + mt * 16 + lr) * 64 + kk + lq * 8];
#pragma unroll
      for (int nt = 0; nt < 4; nt++)
        bfv[nt] = *(const short8*)&Bs[(wn * 64 + nt * 16 + lr) * 64 + kk + lq * 8];
#pragma unroll
      for (int mt = 0; mt < 4; mt++)
#pragma unroll
        for (int nt = 0; nt < 4; nt++)
          acc[mt][nt] = __builtin_amdgcn_mfma_f32_16x16x32_bf16(
              af[mt], bfv[nt], acc[mt][nt], 0, 0, 0);
    }
    __syncthreads();
  }

  float bb[4];
#pragma unroll
  for (int nt = 0; nt < 4; nt++) bb[nt] = bias[n0 + wn * 64 + nt * 16 + lr];
#pragma unroll
  for (int mt = 0; mt < 4; mt++) {
    const int rbase = m0 + wm * 64 + mt * 16 + lq * 4;
#pragma unroll
    for (int nt = 0; nt < 4; nt++) {
      const int col = n0 + wn * 64 + nt * 16 + lr;
#pragma unroll
      for (int r = 0; r < 4; r++) {
        float v = acc[mt][nt][r] + bb[nt];
        size_t idx = (size_t)(rbase + r) * N + col;
        if (EPI) v += resid[idx];
        stc(&C[idx], v);
      }
    }
  }
}

// ---------------------------------------------------------------------------
// Fallback VALU attention (R5-proven, row-major qkv)
// ---------------------------------------------------------------------------
__global__ __launch_bounds__(256) void attn_win(
    const us* __restrict__ qkv, us* __restrict__ attn) {
  __shared__ float qs[64][65];
  __shared__ float ks[64][65];
  __shared__ float vs[64][65];
  const int wid = blockIdx.x;
  const int wi = wid & 63;
  const int h = (wid >> 6) & 15;
  const int b = wid >> 10;
  const int t = threadIdx.x;
  const int rowbase = b * 4096 + wi * 64;
  {
    const int r = t >> 2;
    const int cs = (t & 3) * 16;
    const us* base = qkv + (size_t)(rowbase + r) * 3072 + h * 64 + cs;
#pragma unroll
    for (int s = 0; s < 3; s++) {
      float* dst = (s == 0) ? &qs[r][cs] : (s == 1) ? &ks[r][cs] : &vs[r][cs];
      const us* src = base + s * 1024;
#pragma unroll
      for (int half = 0; half < 2; half++) {
        int4 dv = *(const int4*)(src + half * 8);
        const us* tp = (const us*)&dv;
#pragma unroll
        for (int i = 0; i < 8; i++) dst[half * 8 + i] = bf2f(tp[i]);
      }
    }
  }
  __syncthreads();
  const int r0 = (t >> 4) * 4;
  const int c0 = (t & 15) * 4;
  float acc[4][4] = {};
#pragma unroll 8
  for (int k = 0; k < 64; k++) {
    float qv[4], kv[4];
#pragma unroll
    for (int i = 0; i < 4; i++) qv[i] = qs[r0 + i][k];
#pragma unroll
    for (int j = 0; j < 4; j++) kv[j] = ks[c0 + j][k];
#pragma unroll
    for (int i = 0; i < 4; i++)
#pragma unroll
      for (int j = 0; j < 4; j++) acc[i][j] += qv[i] * kv[j];
  }
  __syncthreads();
#pragma unroll
  for (int i = 0; i < 4; i++)
#pragma unroll
    for (int j = 0; j < 4; j++) qs[r0 + i][c0 + j] = acc[i][j] * 0.125f;
  __syncthreads();
  {
    const int rr = t >> 2;
    const int cs = (t & 3) * 16;
    float pv[16];
    float m = -1e30f;
#pragma unroll
    for (int i = 0; i < 16; i++) {
      pv[i] = qs[rr][cs + i];
      m = fmaxf(m, pv[i]);
    }
    m = fmaxf(m, __shfl_xor(m, 1));
    m = fmaxf(m, __shfl_xor(m, 2));
    float ssum = 0.f;
#pragma unroll
    for (int i = 0; i < 16; i++) {
      pv[i] = __expf(pv[i] - m);
      ssum += pv[i];
    }
    ssum += __shfl_xor(ssum, 1);
    ssum += __shfl_xor(ssum, 2);
    const float inv = 1.0f / ssum;
#pragma unroll
    for (int i = 0; i < 16; i++) qs[rr][cs + i] = pv[i] * inv;
  }
  __syncthreads();
  float o[4][4] = {};
#pragma unroll 8
  for (int k = 0; k < 64; k++) {
    float pr[4], vv[4];
#pragma unroll
    for (int i = 0; i < 4; i++) pr[i] = qs[r0 + i][k];
#pragma unroll
    for (int j = 0; j < 4; j++) vv[j] = vs[k][c0 + j];
#pragma unroll
    for (int i = 0; i < 4; i++)
#pragma unroll
      for (int j = 0; j < 4; j++) o[i][j] += pr[i] * vv[j];
  }
#pragma unroll
  for (int i = 0; i < 4; i++)
#pragma unroll
    for (int j = 0; j < 4; j++)
      attn[(size_t)(rowbase + r0 + i) * 1024 + h * 64 + c0 + j] = f2bf(o[i][j]);
}

// ---------------------------------------------------------------------------
// In-place fp32 LayerNorm, one WAVE per row: no LDS, no barriers.
// ---------------------------------------------------------------------------
__global__ __launch_bounds__(256) void ln_wave(
    float* __restrict__ y, const float* __restrict__ gamma,
    const float* __restrict__ beta) {
  const int row = blockIdx.x * 4 + (threadIdx.x >> 6);
  const int lane = threadIdx.x & 63;
  float* yr = y + (size_t)row * 1024;
  float4 v[4];
  float s1 = 0.f, s2 = 0.f;
#pragma unroll
  for (int i = 0; i < 4; i++) {
    v[i] = *(const float4*)(yr + (i * 64 + lane) * 4);
    s1 += v[i].x + v[i].y + v[i].z + v[i].w;
    s2 += v[i].x * v[i].x + v[i].y * v[i].y + v[i].z * v[i].z + v[i].w * v[i].w;
  }
#pragma unroll
  for (int off = 32; off > 0; off >>= 1) {
    s1 += __shfl_xor(s1, off);
    s2 += __shfl_xor(s2, off);
  }
  const float mean = s1 * (1.0f / 1024.0f);
  const float var = s2 * (1.0f / 1024.0f) - mean * mean;
  const float rstd = rsqrtf(var + 1e-5f);
#pragma unroll
  for (int i = 0; i < 4; i++) {
    float4 g = *(const float4*)(gamma + (i * 64 + lane) * 4);
    float4 bt = *(const float4*)(beta + (i * 64 + lane) * 4);
    float4 o;
    o.x = (v[i].x - mean) * rstd * g.x + bt.x;
    o.y = (v[i].y - mean) * rstd * g.y + bt.y;
    o.z = (v[i].z - mean) * rstd * g.z + bt.z;
    o.w = (v[i].w - mean) * rstd * g.w + bt.w;
    *(float4*)(yr + (i * 64 + lane) * 4) = o;
  }
}

// ---------------------------------------------------------------------------
extern "C" void kernel_launch(void* const* d_in, const int* in_sizes, int n_in,
                              void* d_out, int out_size, void* d_ws,
                              size_t ws_size, hipStream_t stream) {
  const float* x = (const float*)d_in[0];
  const float* Wqkv = (const float*)d_in[1];
  const float* bqkv = (const float*)d_in[2];
  const float* Wproj = (const float*)d_in[3];
  const float* bproj = (const float*)d_in[4];
  const float* gamma = (const float*)d_in[5];
  const float* beta = (const float*)d_in[6];
  float* out = (float*)d_out;

  us* qkv = (us*)d_ws;                        // 16384*3072 (100.7 MB)
  us* attn = qkv + (size_t)16384 * 3072;      // 16384*1024 (33.6 MB)
  us* xb = attn + (size_t)16384 * 1024;       // 16384*1024 (33.6 MB)
  us* Wqkvb = xb + (size_t)16384 * 1024;      // 3072*1024  (6.3 MB)
  us* Wprojb = Wqkvb + (size_t)3072 * 1024;   // 1024*1024  (2.1 MB)
  const size_t need =
      ((size_t)16384 * 3072 + 3 * (size_t)16384 * 1024 + (size_t)3072 * 1024 +
       (size_t)1024 * 1024) * sizeof(us);

  if (ws_size >= need) {
    constexpr int ncast = 16384 * 128 + 3072 * 128 + 1024 * 128;  // 8-elem units
    cast_all<<<ncast / 256, 256, 0, stream>>>(x, Wqkv, Wproj, xb, Wqkvb,
                                              Wprojb);
    gemm256<3072, 1024, 0, 1, us><<<dim3(12, 64), 512, 0, stream>>>(
        xb, Wqkvb, bqkv, nullptr, qkv);
    attn_mfma<<<4096, 256, 0, stream>>>(qkv, attn);
    gemm256<1024, 1024, 1, 0, float><<<dim3(4, 64), 512, 0, stream>>>(
        attn, Wprojb, bproj, x, out);
  } else {
    gemm_bt<3072, 1024, 0, float, us><<<dim3(24, 128), 256, 0, stream>>>(
        x, Wqkv, bqkv, nullptr, qkv);
    attn_win<<<4096, 256, 0, stream>>>(qkv, attn);
    gemm_bt<1024, 1024, 1, us, float><<<dim3(8, 128), 256, 0, stream>>>(
        attn, Wproj, bproj, x, out);
  }
  ln_wave<<<4096, 256, 0, stream>>>(out, gamma, beta);
}